// Round 12
// baseline (460.371 us; speedup 1.0000x reference)
//
#include <hip/hip_runtime.h>

#define HWc   262144   // 512*512
#define CGc   128
#define CHc   64
#define COc   32
#define NPIXc 524288   // B*H*W
#define TW 32
#define TH 8
#define HLW 38         // TW+6
#define HLH 14         // TH+6
#define HPX (HLW*HLH)  // 532
#define HPAD 545       // padded plane stride (4-bank offset per plane)

typedef _Float16 h2    __attribute__((ext_vector_type(2)));
typedef __fp16   fp2   __attribute__((ext_vector_type(2)));
typedef _Float16 f16x4 __attribute__((ext_vector_type(4)));
typedef _Float16 f16x8 __attribute__((ext_vector_type(8)));
typedef float    f32x4 __attribute__((ext_vector_type(4)));

union AB  { uint4 q; f16x8 v; h2 p[4]; unsigned u[4]; };
union AB4 { uint2 q; f16x4 v; h2 p[2]; unsigned u[2]; };

__device__ __forceinline__ int refl(int p){
  if (p < 0) p = -p;
  else if (p >= 512) p = 1022 - p;
  return p;
}
__device__ __forceinline__ h2 as_h2(unsigned u){ union{unsigned u; h2 h;} x; x.u = u; return x.h; }
__device__ __forceinline__ unsigned as_u(h2 h){ union{unsigned u; h2 h;} x; x.h = h; return x.u; }
__device__ __forceinline__ unsigned pkh(float a, float b){       // RNE pack
  h2 h; h.x = (_Float16)a; h.y = (_Float16)b; return as_u(h);
}
__device__ __forceinline__ h2 pkrtz(float a, float b){           // v_cvt_pkrtz
  union{ fp2 f; h2 h; } x; x.f = __builtin_amdgcn_cvt_pkrtz(a, b); return x.h;
}
__device__ __forceinline__ float2 upk(unsigned u){
  h2 h = as_h2(u); return make_float2((float)h.x, (float)h.y);
}
__device__ __forceinline__ f32x4 mfma32(f16x8 a, f16x8 b, f32x4 c){
  return __builtin_amdgcn_mfma_f32_16x16x32_f16(a, b, c, 0, 0, 0);
}
__device__ __forceinline__ f32x4 mfma16(f16x4 a, f16x4 b, f32x4 c){
  return __builtin_amdgcn_mfma_f32_16x16x16f16(a, b, c, 0, 0, 0);
}

// -------- K0: sigma; pack wg and w_sn into MFMA A-fragment order ----------------------
__global__ void k0_prep(const float* __restrict__ wbar, const float* __restrict__ u,
                        const float* __restrict__ wg,
                        unsigned* __restrict__ wgA, unsigned* __restrict__ wsnA){
  const int t = threadIdx.x;
  __shared__ float sv1[32];
  float tv = 0.f;
  if (t < 32){
    #pragma unroll
    for (int o = 0; o < 32; o++) tv += wbar[o*32 + t] * u[o];
  }
  float sq = tv * tv;
  #pragma unroll
  for (int off = 32; off; off >>= 1) sq += __shfl_down(sq, off);
  const float n1 = sqrtf(__shfl(sq, 0)) + 1e-12f;
  if (t < 32) sv1[t] = tv / n1;
  __syncthreads();
  float tu = 0.f;
  if (t < 32){
    #pragma unroll
    for (int c = 0; c < 32; c++) tu += wbar[t*32 + c] * sv1[c];
  }
  float sq2 = tu * tu;
  #pragma unroll
  for (int off = 32; off; off >>= 1) sq2 += __shfl_down(sq2, off);
  const float S = __shfl(sq2, 0);
  const float inv = (sqrtf(S) + 1e-12f) / S;     // 1/sigma

  for (int k = t; k < 4096; k += 64){
    const int mk = k >> 8, L = (k >> 2) & 63, j = k & 3;
    const int m = mk >> 2, ks = mk & 3;
    const int o = m*16 + (L & 15);
    const int c = ks*32 + 8*(L >> 4) + 2*j;
    wgA[k] = pkh(wg[o*128 + c], wg[o*128 + c + 1]);
  }
  for (int k = t; k < 512; k += 64){
    const int m = k >> 8, L = (k >> 2) & 63, j = k & 3;
    const int o = m*16 + (L & 15);
    const int c = 8*(L >> 4) + 2*j;
    wsnA[k] = pkh(wbar[o*32 + c] * inv, wbar[o*32 + c + 1] * inv);
  }
}

// -------- K1m: MFMA {conv+norm -> gn px-major} and {alpha' -> CH-MAJOR f16} ----------
__global__ __launch_bounds__(256) void k1m(const float* __restrict__ f,
                                           const float* __restrict__ alpha,
                                           const uint4* __restrict__ wgA,
                                           const uint4* __restrict__ wsnA,
                                           const float* __restrict__ bg,
                                           unsigned* __restrict__ gn,
                                           _Float16* __restrict__ aph){
  const int tid  = threadIdx.x;
  const int lane = tid & 63, w = tid >> 6;
  const int lo   = lane & 15, hi = lane >> 4;

  AB wga[4][4];
  #pragma unroll
  for (int m = 0; m < 4; m++)
    #pragma unroll
    for (int ks = 0; ks < 4; ks++)
      wga[m][ks].q = wgA[(m*4 + ks)*64 + lane];
  AB wsa[2];
  #pragma unroll
  for (int m = 0; m < 2; m++) wsa[m].q = wsnA[m*64 + lane];
  float4 bgl[4];
  #pragma unroll
  for (int m = 0; m < 4; m++) bgl[m] = *(const float4*)(bg + m*16 + hi*4);

  const int pxg = blockIdx.x * 256 + w * 64;

  #pragma unroll 1
  for (int nt = 0; nt < 4; nt++){
    const int px0  = pxg + nt*16;
    const int b    = px0 >> 18;
    const int pix0 = px0 & (HWc - 1);
    const float* fb = f + (size_t)b * CGc * HWc + pix0 + lo;
    const float* ac = alpha + (size_t)b * COc * HWc + pix0 + lo + (size_t)(hi*8) * HWc;

    float fv[32], av[8];
    #pragma unroll
    for (int ks = 0; ks < 4; ks++){
      const float* fc = fb + (size_t)(ks*32 + hi*8) * HWc;
      #pragma unroll
      for (int e = 0; e < 8; e++)
        fv[ks*8 + e] = fc[(size_t)e * HWc];
    }
    #pragma unroll
    for (int e = 0; e < 8; e++)
      av[e] = ac[(size_t)e * HWc];

    f32x4 acc[4];
    #pragma unroll
    for (int m = 0; m < 4; m++) acc[m] = (f32x4){0.f, 0.f, 0.f, 0.f};

    #pragma unroll
    for (int ks = 0; ks < 4; ks++){
      AB bf;
      #pragma unroll
      for (int j = 0; j < 4; j++)
        bf.p[j] = pkrtz(fv[ks*8 + 2*j], fv[ks*8 + 2*j + 1]);
      #pragma unroll
      for (int m = 0; m < 4; m++)
        acc[m] = mfma32(wga[m][ks].v, bf.v, acc[m]);
    }

    float v[16]; float nsq = 0.f;
    #pragma unroll
    for (int m = 0; m < 4; m++){
      v[4*m+0] = acc[m][0] + bgl[m].x;
      v[4*m+1] = acc[m][1] + bgl[m].y;
      v[4*m+2] = acc[m][2] + bgl[m].z;
      v[4*m+3] = acc[m][3] + bgl[m].w;
      nsq = fmaf(v[4*m+0], v[4*m+0], nsq); nsq = fmaf(v[4*m+1], v[4*m+1], nsq);
      nsq = fmaf(v[4*m+2], v[4*m+2], nsq); nsq = fmaf(v[4*m+3], v[4*m+3], nsq);
    }
    nsq += __shfl_xor(nsq, 16);
    nsq += __shfl_xor(nsq, 32);
    const float inv = 1.f / fmaxf(sqrtf(nsq), 1e-4f);

    unsigned* gp = gn + (size_t)(px0 + lo) * 32 + hi*2;
    #pragma unroll
    for (int m = 0; m < 4; m++){
      uint2 st = make_uint2(pkh(v[4*m+0]*inv, v[4*m+1]*inv),
                            pkh(v[4*m+2]*inv, v[4*m+3]*inv));
      *(uint2*)(gp + m*8) = st;
    }

    // alpha' = W_sn * alpha -> CH-MAJOR f16: aph[(b*32+ch)*HW + pix]
    AB af;
    #pragma unroll
    for (int j = 0; j < 4; j++)
      af.p[j] = pkrtz(av[2*j], av[2*j + 1]);
    #pragma unroll
    for (int m = 0; m < 2; m++){
      f32x4 aa = (f32x4){0.f, 0.f, 0.f, 0.f};
      aa = mfma32(wsa[m].v, af.v, aa);
      #pragma unroll
      for (int r = 0; r < 4; r++)
        aph[((size_t)((b << 5) + m*16 + hi*4 + r) << 18) + pix0 + lo] = (_Float16)aa[r];
    }
  }
}

// -------- K2: banded-attention MFMA correlation + softmax + aggregation --------------
// S^T = G_n * G_c (16x16x32): D lane = (c=lane&15, n=4*(lane>>4)+reg)
// E = exp(S^T) band-masked; cvt_pk pairs -> directly B-frag of K=16 PV MFMA.
// Y^T = Aph * E (16x16x16): D lane = (c=lane&15, ch=4*(lane>>4)+reg)
// n-origin: n=0 <-> img col x0+cs-4 (alignment); j = n - lo - 1 in [0,6].
__global__ __launch_bounds__(256) void k2_agg(const unsigned* __restrict__ gn,
                                              const _Float16* __restrict__ aph,
                                              unsigned* __restrict__ y2){
  __shared__ uint4 gs4[8][HPAD];   // 69.7 KB, plane stride 545

  const int lb  = (blockIdx.x & 7) * 256 + (blockIdx.x >> 3);   // XCD-chunked swizzle
  const int txx = lb & 15;
  const int tyy = (lb >> 4) & 63;
  const int bb  = lb >> 10;
  const int x0  = txx * TW, y0 = tyy * TH;
  const int tid = threadIdx.x;

  for (int t = tid; t < HPX; t += 256){
    const int hr = t / HLW;
    const int hc = t - hr * HLW;
    const int gy = refl(y0 + hr - 3);
    const int gx = refl(x0 + hc - 3);
    const uint4* src = (const uint4*)(gn + (size_t)((bb << 18) + (gy << 9) + gx) * 32);
    #pragma unroll
    for (int k = 0; k < 8; k++) gs4[k][t] = src[k];
  }
  __syncthreads();

  const int lane = tid & 63, w = tid >> 6;
  const int lo   = lane & 15, hi = lane >> 4;
  const bool interior = (txx != 0) && (txx != 15);

  #pragma unroll 1
  for (int q = 0; q < 4; q++){
    const int sid = w*4 + q;
    const int rs  = sid >> 1;
    const int cs  = (sid & 1) * 16;

    // centers B-frags (B[k=ch][col=c]): cached across i
    const int self = (rs + 3)*HLW + cs + 3 + lo;
    AB bc0, bc1;
    bc0.q = gs4[hi][self];
    bc1.q = gs4[4 + hi][self];

    f32x4 pv0 = (f32x4){0.f,0.f,0.f,0.f}, pv1 = (f32x4){0.f,0.f,0.f,0.f};
    float esp = 0.f;

    #pragma unroll 1
    for (int i = 0; i < 7; i++){
      const int rowb = (rs + i)*HLW + cs - 1;   // halo col of n=0

      int ia0 = rowb + lo;       ia0 = ia0 < 0 ? 0 : (ia0 > HPAD-1 ? HPAD-1 : ia0);
      int ia1 = rowb + 16 + lo;  ia1 = ia1 < 0 ? 0 : (ia1 > HPAD-1 ? HPAD-1 : ia1);
      AB an00, an01, an10, an11;
      an00.q = gs4[hi][ia0]; an01.q = gs4[4 + hi][ia0];
      an10.q = gs4[hi][ia1]; an11.q = gs4[4 + hi][ia1];

      f32x4 s0 = mfma32(an00.v, bc0.v, (f32x4){0.f,0.f,0.f,0.f});
      s0 = mfma32(an01.v, bc1.v, s0);
      f32x4 s1 = mfma32(an10.v, bc0.v, (f32x4){0.f,0.f,0.f,0.f});
      s1 = mfma32(an11.v, bc1.v, s1);

      const int gy = refl(y0 + rs + i - 3);
      // PV A-frags (A[m=ch][k=n]) from ch-major alpha': issue before exp
      AB4 pa00, pa01, pa10, pa11;
      {
        const size_t r0 = ((size_t)((bb << 5) + lo)      << 18) + (gy << 9);
        const size_t r1 = ((size_t)((bb << 5) + 16 + lo) << 18) + (gy << 9);
        const int c0 = x0 + cs - 4 + 4*hi;
        if (interior){
          pa00.v = *(const f16x4*)(aph + r0 + c0);
          pa01.v = *(const f16x4*)(aph + r0 + c0 + 16);
          pa10.v = *(const f16x4*)(aph + r1 + c0);
          pa11.v = *(const f16x4*)(aph + r1 + c0 + 16);
        } else {
          #pragma unroll
          for (int e = 0; e < 4; e++){
            const int ca = refl(c0 + e), cb = refl(c0 + 16 + e);
            pa00.v[e] = aph[r0 + ca]; pa01.v[e] = aph[r0 + cb];
            pa10.v[e] = aph[r1 + ca]; pa11.v[e] = aph[r1 + cb];
          }
        }
      }

      // exp + band mask: j = n - lo - 1 valid in [0,6]; skip center (i==3, j==3)
      float e0[4], e1[4];
      #pragma unroll
      for (int r = 0; r < 4; r++){
        const int n0 = 4*hi + r, n1 = 16 + 4*hi + r;
        const int j0 = n0 - lo - 1, j1 = n1 - lo - 1;
        const bool v0 = (j0 >= 0) && (j0 <= 6) && !(i == 3 && j0 == 3);
        const bool v1 = (j1 >= 0) && (j1 <= 6) && !(i == 3 && j1 == 3);
        e0[r] = v0 ? __expf(s0[r]) : 0.f;
        e1[r] = v1 ? __expf(s1[r]) : 0.f;
        esp += e0[r] + e1[r];
      }
      AB4 eb0, eb1;
      eb0.p[0] = pkrtz(e0[0], e0[1]); eb0.p[1] = pkrtz(e0[2], e0[3]);
      eb1.p[0] = pkrtz(e1[0], e1[1]); eb1.p[1] = pkrtz(e1[2], e1[3]);

      pv0 = mfma16(pa00.v, eb0.v, pv0);
      pv0 = mfma16(pa01.v, eb1.v, pv0);
      pv1 = mfma16(pa10.v, eb0.v, pv1);
      pv1 = mfma16(pa11.v, eb1.v, pv1);
    }

    esp += __shfl_xor(esp, 16);
    esp += __shfl_xor(esp, 32);
    const float inv = 1.f / esp;

    const size_t px = (size_t)((bb << 18) + ((y0 + rs) << 9) + x0 + cs + lo);
    uint2 st0 = make_uint2(pkh(pv0[0]*inv, pv0[1]*inv), pkh(pv0[2]*inv, pv0[3]*inv));
    uint2 st1 = make_uint2(pkh(pv1[0]*inv, pv1[1]*inv), pkh(pv1[2]*inv, pv1[3]*inv));
    *(uint2*)(y2 + px*16 + 2*hi)     = st0;
    *(uint2*)(y2 + px*16 + 8 + 2*hi) = st1;
  }
}

// -------- K3: BN stats over f16 y2 ---------------------------------------------------
__global__ __launch_bounds__(256) void k3_stats(const unsigned* __restrict__ y2,
                                                float* __restrict__ stats){
  float s[COc], q[COc];
  #pragma unroll
  for (int o = 0; o < COc; o++){ s[o] = 0.f; q[o] = 0.f; }
  const int stride = gridDim.x * 256;
  for (int p = blockIdx.x * 256 + threadIdx.x; p < NPIXc; p += stride){
    const uint4* yp = (const uint4*)(y2 + (size_t)p * 16);
    #pragma unroll
    for (int k = 0; k < 4; k++){
      const uint4 w = yp[k];
      const unsigned vv[4] = {w.x, w.y, w.z, w.w};
      #pragma unroll
      for (int m = 0; m < 4; m++){
        const float2 ab = upk(vv[m]);
        s[8*k+2*m]   += ab.x; q[8*k+2*m]   = fmaf(ab.x, ab.x, q[8*k+2*m]);
        s[8*k+2*m+1] += ab.y; q[8*k+2*m+1] = fmaf(ab.y, ab.y, q[8*k+2*m+1]);
      }
    }
  }
  #pragma unroll
  for (int o = 0; o < COc; o++){
    #pragma unroll
    for (int off = 32; off; off >>= 1){
      s[o] += __shfl_down(s[o], off);
      q[o] += __shfl_down(q[o], off);
    }
  }
  __shared__ float red[4][64];
  const int wv = threadIdx.x >> 6;
  if ((threadIdx.x & 63) == 0){
    #pragma unroll
    for (int o = 0; o < COc; o++){ red[wv][o] = s[o]; red[wv][32 + o] = q[o]; }
  }
  __syncthreads();
  if (threadIdx.x < 64){
    const float v = red[0][threadIdx.x] + red[1][threadIdx.x]
                  + red[2][threadIdx.x] + red[3][threadIdx.x];
    atomicAdd(&stats[threadIdx.x], v);
  }
}

// -------- K3b: stats -> (mean, 0.1*rsqrt(var+eps)) ------------------------------------
__global__ void k3b_final(const float* __restrict__ stats, float* __restrict__ stats2){
  const int t = threadIdx.x;
  if (t < COc){
    const float invN = 1.f / (float)NPIXc;
    const float mean = stats[t] * invN;
    const float var  = fmaf(-mean, mean, stats[COc + t] * invN);
    stats2[t]       = mean;
    stats2[COc + t] = 0.1f * rsqrtf(var + 1e-5f);
  }
}

// -------- K4: BatchNorm + residual ----------------------------------------------------
__global__ __launch_bounds__(256) void k4_out(const unsigned* __restrict__ y2,
                                              const float* __restrict__ alpha,
                                              const float* __restrict__ stats2,
                                              float* __restrict__ out){
  const int p   = blockIdx.x * 256 + threadIdx.x;
  const int b   = p >> 18;
  const int pix = p & (HWc - 1);
  const uint4* yp = (const uint4*)(y2 + (size_t)p * 16);
  const size_t boff = (size_t)b * COc * HWc + pix;
  #pragma unroll
  for (int k = 0; k < 4; k++){
    const uint4 w = yp[k];
    const unsigned vv[4] = {w.x, w.y, w.z, w.w};
    #pragma unroll
    for (int m = 0; m < 4; m++){
      const int o = 8*k + 2*m;
      const float2 ab = upk(vv[m]);
      out[boff + (size_t)o*HWc]     = fmaf(ab.x - stats2[o],   stats2[COc+o],
                                           alpha[boff + (size_t)o*HWc]);
      out[boff + (size_t)(o+1)*HWc] = fmaf(ab.y - stats2[o+1], stats2[COc+o+1],
                                           alpha[boff + (size_t)(o+1)*HWc]);
    }
  }
}

extern "C" void kernel_launch(void* const* d_in, const int* in_sizes, int n_in,
                              void* d_out, int out_size, void* d_ws, size_t ws_size,
                              hipStream_t stream){
  const float* f     = (const float*)d_in[0];
  const float* alpha = (const float*)d_in[1];
  const float* wg    = (const float*)d_in[2];
  const float* bg    = (const float*)d_in[3];
  const float* wbar  = (const float*)d_in[4];
  const float* u     = (const float*)d_in[5];
  (void)in_sizes; (void)n_in; (void)out_size; (void)ws_size;
  float* out = (float*)d_out;

  char* ws = (char*)d_ws;
  float*     stats  = (float*)ws;                       // 256 B
  float*     stats2 = (float*)(ws + 4096);              // 256 B
  unsigned*  wgA    = (unsigned*)(ws + 8192);           // 16 KB
  unsigned*  wsnA   = (unsigned*)(ws + 32768);          // 2 KB
  _Float16*  aph    = (_Float16*)(ws + 65536);                                  // 32 MB ch-major
  unsigned*  gn     = (unsigned*)(ws + 65536 + (size_t)NPIXc*64);               // 64 MB
  unsigned*  y2     = (unsigned*)(ws + 65536 + (size_t)NPIXc*64 + (size_t)NPIXc*128); // 32 MB

  (void)hipMemsetAsync(stats, 0, 64 * sizeof(float), stream);
  k0_prep  <<<1, 64, 0, stream>>>(wbar, u, wg, wgA, wsnA);
  k1m      <<<NPIXc / 256, 256, 0, stream>>>(f, alpha, (const uint4*)wgA,
                                             (const uint4*)wsnA, bg, gn, aph);
  k2_agg   <<<2048, 256, 0, stream>>>(gn, aph, y2);
  k3_stats <<<256, 256, 0, stream>>>(y2, stats);
  k3b_final<<<1, 64, 0, stream>>>(stats, stats2);
  k4_out   <<<NPIXc / 256, 256, 0, stream>>>(y2, alpha, stats2, out);
}

// Round 13
// 311.114 us; speedup vs baseline: 1.4798x; 1.4798x over previous
//
#include <hip/hip_runtime.h>

#define HWc   262144   // 512*512
#define CGc   128
#define CHc   64
#define COc   32
#define NPIXc 524288   // B*H*W
#define TW 32
#define TH 8
#define HLW 38         // TW+6
#define HLH 14         // TH+6
#define HPX (HLW*HLH)  // 532

typedef _Float16 h2    __attribute__((ext_vector_type(2)));
typedef __fp16   fp2   __attribute__((ext_vector_type(2)));
typedef _Float16 f16x8 __attribute__((ext_vector_type(8)));
typedef float    f32x4 __attribute__((ext_vector_type(4)));

union AB { uint4 q; f16x8 v; h2 p[4]; unsigned u[4]; };

__device__ __forceinline__ int refl(int p){
  if (p < 0) p = -p;
  else if (p >= 512) p = 1022 - p;
  return p;
}
__device__ __forceinline__ h2 as_h2(unsigned u){ union{unsigned u; h2 h;} x; x.u = u; return x.h; }
__device__ __forceinline__ unsigned as_u(h2 h){ union{unsigned u; h2 h;} x; x.h = h; return x.u; }
__device__ __forceinline__ unsigned pkh(float a, float b){       // RNE pack
  h2 h; h.x = (_Float16)a; h.y = (_Float16)b; return as_u(h);
}
__device__ __forceinline__ h2 pkrtz(float a, float b){           // v_cvt_pkrtz
  union{ fp2 f; h2 h; } x; x.f = __builtin_amdgcn_cvt_pkrtz(a, b); return x.h;
}
__device__ __forceinline__ float2 upk(unsigned u){
  h2 h = as_h2(u); return make_float2((float)h.x, (float)h.y);
}
__device__ __forceinline__ float dot2h(unsigned a, unsigned b, float c){
  return __builtin_amdgcn_fdot2(as_h2(a), as_h2(b), c, false);
}
__device__ __forceinline__ void mixlo(float& acc, unsigned ab, float e){
  asm("v_fma_mix_f32 %0, %1, %2, %0 op_sel:[0,0,0] op_sel_hi:[1,0,0]"
      : "+v"(acc) : "v"(ab), "v"(e));
}
__device__ __forceinline__ void mixhi(float& acc, unsigned ab, float e){
  asm("v_fma_mix_f32 %0, %1, %2, %0 op_sel:[1,0,0] op_sel_hi:[1,0,0]"
      : "+v"(acc) : "v"(ab), "v"(e));
}
__device__ __forceinline__ f32x4 mfma32(f16x8 a, f16x8 b, f32x4 c){
  return __builtin_amdgcn_mfma_f32_16x16x32_f16(a, b, c, 0, 0, 0);
}

// -------- K0: sigma; pack wg and w_sn into MFMA A-fragment order ----------------------
// A-frag (16x16x32 f16): lane L holds row o = L&15, k = 8*(L>>4)+e, e=0..7.
__global__ void k0_prep(const float* __restrict__ wbar, const float* __restrict__ u,
                        const float* __restrict__ wg,
                        unsigned* __restrict__ wgA, unsigned* __restrict__ wsnA){
  const int t = threadIdx.x;
  __shared__ float sv1[32];
  float tv = 0.f;
  if (t < 32){
    #pragma unroll
    for (int o = 0; o < 32; o++) tv += wbar[o*32 + t] * u[o];
  }
  float sq = tv * tv;
  #pragma unroll
  for (int off = 32; off; off >>= 1) sq += __shfl_down(sq, off);
  const float n1 = sqrtf(__shfl(sq, 0)) + 1e-12f;
  if (t < 32) sv1[t] = tv / n1;
  __syncthreads();
  float tu = 0.f;
  if (t < 32){
    #pragma unroll
    for (int c = 0; c < 32; c++) tu += wbar[t*32 + c] * sv1[c];
  }
  float sq2 = tu * tu;
  #pragma unroll
  for (int off = 32; off; off >>= 1) sq2 += __shfl_down(sq2, off);
  const float S = __shfl(sq2, 0);
  const float inv = (sqrtf(S) + 1e-12f) / S;     // 1/sigma

  for (int k = t; k < 4096; k += 64){
    const int mk = k >> 8, L = (k >> 2) & 63, j = k & 3;
    const int m = mk >> 2, ks = mk & 3;
    const int o = m*16 + (L & 15);
    const int c = ks*32 + 8*(L >> 4) + 2*j;
    wgA[k] = pkh(wg[o*128 + c], wg[o*128 + c + 1]);
  }
  for (int k = t; k < 512; k += 64){
    const int m = k >> 8, L = (k >> 2) & 63, j = k & 3;
    const int o = m*16 + (L & 15);
    const int c = 8*(L >> 4) + 2*j;
    wsnA[k] = pkh(wbar[o*32 + c] * inv, wbar[o*32 + c + 1] * inv);
  }
}

// -------- K1m: MFMA conv+norm / alpha' — 2-tile software pipeline (T14) ---------------
__global__ __launch_bounds__(256) void k1m(const float* __restrict__ f,
                                           const float* __restrict__ alpha,
                                           const uint4* __restrict__ wgA,
                                           const uint4* __restrict__ wsnA,
                                           const float* __restrict__ bg,
                                           unsigned* __restrict__ gn,
                                           unsigned* __restrict__ apm){
  const int tid  = threadIdx.x;
  const int lane = tid & 63, w = tid >> 6;
  const int lo   = lane & 15, hi = lane >> 4;

  AB wga[4][4];
  #pragma unroll
  for (int m = 0; m < 4; m++)
    #pragma unroll
    for (int ks = 0; ks < 4; ks++)
      wga[m][ks].q = wgA[(m*4 + ks)*64 + lane];
  AB wsa[2];
  #pragma unroll
  for (int m = 0; m < 2; m++) wsa[m].q = wsnA[m*64 + lane];
  float4 bgl[4];
  #pragma unroll
  for (int m = 0; m < 4; m++) bgl[m] = *(const float4*)(bg + m*16 + hi*4);

  const int pxg = blockIdx.x * 256 + w * 64;

  // ---- issue all 40 loads of tile nt into named register arrays ----
  auto loadT = [&](int nt, float* fv, float* av){
    const int px0  = pxg + nt*16;
    const int b    = px0 >> 18;
    const int pix0 = px0 & (HWc - 1);
    const float* fb = f + (size_t)b * CGc * HWc + pix0 + lo;
    const float* ac = alpha + (size_t)b * COc * HWc + pix0 + lo + (size_t)(hi*8) * HWc;
    #pragma unroll
    for (int ks = 0; ks < 4; ks++){
      const float* fc = fb + (size_t)(ks*32 + hi*8) * HWc;
      #pragma unroll
      for (int e = 0; e < 8; e++)
        fv[ks*8 + e] = fc[(size_t)e * HWc];
    }
    #pragma unroll
    for (int e = 0; e < 8; e++)
      av[e] = ac[(size_t)e * HWc];
  };

  // ---- convert + MFMA + norm + store for tile nt ----
  auto procT = [&](int nt, const float* fv, const float* av){
    const int px0  = pxg + nt*16;
    const int b    = px0 >> 18;
    const int pix0 = px0 & (HWc - 1);
    (void)b; (void)pix0;

    f32x4 acc[4];
    #pragma unroll
    for (int m = 0; m < 4; m++) acc[m] = (f32x4){0.f, 0.f, 0.f, 0.f};

    #pragma unroll
    for (int ks = 0; ks < 4; ks++){
      AB bf;
      #pragma unroll
      for (int j = 0; j < 4; j++)
        bf.p[j] = pkrtz(fv[ks*8 + 2*j], fv[ks*8 + 2*j + 1]);
      #pragma unroll
      for (int m = 0; m < 4; m++)
        acc[m] = mfma32(wga[m][ks].v, bf.v, acc[m]);
    }

    float v[16]; float nsq = 0.f;
    #pragma unroll
    for (int m = 0; m < 4; m++){
      v[4*m+0] = acc[m][0] + bgl[m].x;
      v[4*m+1] = acc[m][1] + bgl[m].y;
      v[4*m+2] = acc[m][2] + bgl[m].z;
      v[4*m+3] = acc[m][3] + bgl[m].w;
      nsq = fmaf(v[4*m+0], v[4*m+0], nsq); nsq = fmaf(v[4*m+1], v[4*m+1], nsq);
      nsq = fmaf(v[4*m+2], v[4*m+2], nsq); nsq = fmaf(v[4*m+3], v[4*m+3], nsq);
    }
    nsq += __shfl_xor(nsq, 16);
    nsq += __shfl_xor(nsq, 32);
    const float inv = 1.f / fmaxf(sqrtf(nsq), 1e-4f);

    unsigned* gp = gn + (size_t)(px0 + lo) * 32 + hi*2;
    #pragma unroll
    for (int m = 0; m < 4; m++){
      uint2 st = make_uint2(pkh(v[4*m+0]*inv, v[4*m+1]*inv),
                            pkh(v[4*m+2]*inv, v[4*m+3]*inv));
      *(uint2*)(gp + m*8) = st;
    }

    AB af;
    #pragma unroll
    for (int j = 0; j < 4; j++)
      af.p[j] = pkrtz(av[2*j], av[2*j + 1]);
    unsigned* op = apm + (size_t)(px0 + lo) * 16 + hi*2;
    #pragma unroll
    for (int m = 0; m < 2; m++){
      f32x4 aa = (f32x4){0.f, 0.f, 0.f, 0.f};
      aa = mfma32(wsa[m].v, af.v, aa);
      uint2 st = make_uint2(pkh(aa[0], aa[1]), pkh(aa[2], aa[3]));
      *(uint2*)(op + m*8) = st;
    }
  };

  // ---- 2-deep pipeline: loads of nt+1 in flight under process(nt) ----
  float fv0[32], av0[8], fv1[32], av1[8];
  loadT(0, fv0, av0);
  loadT(1, fv1, av1);
  procT(0, fv0, av0);
  loadT(2, fv0, av0);
  procT(1, fv1, av1);
  loadT(3, fv1, av1);
  procT(2, fv0, av0);
  procT(3, fv1, av1);
}

// -------- K2: single-phase dot2 correlation + softmax + agg -> y2 f16 (R8, proven) ---
__global__ __launch_bounds__(256) void k2_agg(const unsigned* __restrict__ gn,
                                              const unsigned* __restrict__ apm,
                                              unsigned* __restrict__ y2){
  __shared__ uint4 gs4[8][HPX];   // 68 KB: full halo, 8 channel-pair planes

  const int lb  = (blockIdx.x & 7) * 256 + (blockIdx.x >> 3);   // XCD-chunked swizzle
  const int txx = lb & 15;
  const int tyy = (lb >> 4) & 63;
  const int bb  = lb >> 10;
  const int x0  = txx * TW, y0 = tyy * TH;
  const int tid = threadIdx.x;

  for (int t = tid; t < HPX; t += 256){
    const int hr = t / HLW;
    const int hc = t - hr * HLW;
    const int gy = refl(y0 + hr - 3);
    const int gx = refl(x0 + hc - 3);
    const uint4* src = (const uint4*)(gn + (size_t)((bb << 18) + (gy << 9) + gx) * 32);
    #pragma unroll
    for (int k = 0; k < 8; k++) gs4[k][t] = src[k];
  }
  __syncthreads();

  const int r  = tid >> 5, c = tid & 31;
  const int yy = y0 + r,  xx = x0 + c;
  const int self = (r + 3) * HLW + (c + 3);

  uint4 cv[8];
  #pragma unroll
  for (int k = 0; k < 8; k++) cv[k] = gs4[k][self];

  int ax[7];
  #pragma unroll
  for (int j = 0; j < 7; j++) ax[j] = refl(xx + j - 3);

  float yac[COc];
  #pragma unroll
  for (int k = 0; k < COc; k++) yac[k] = 0.f;
  float esum = 0.f;

  #pragma unroll 1
  for (int i = 0; i < 7; i++){
    const int ay = refl(yy + i - 3);
    const unsigned* aprow = apm + (size_t)((bb << 18) + (ay << 9)) * 16;
    const int rowbase = (r + i) * HLW + c;
    #pragma unroll
    for (int j = 0; j < 7; j++){
      if (i == 3 && j == 3) continue;          // center tap: exp(-10000) == 0
      const int hp = rowbase + j;
      float s0 = 0.f, s1 = 0.f, s2 = 0.f, s3 = 0.f;
      #pragma unroll
      for (int k = 0; k < 8; k++){
        const uint4 q = gs4[k][hp];
        s0 = dot2h(cv[k].x, q.x, s0);
        s1 = dot2h(cv[k].y, q.y, s1);
        s2 = dot2h(cv[k].z, q.z, s2);
        s3 = dot2h(cv[k].w, q.w, s3);
      }
      const float e = __expf((s0 + s1) + (s2 + s3));
      esum += e;
      const uint4* ap = (const uint4*)(aprow + (size_t)ax[j] * 16);
      #pragma unroll
      for (int kk = 0; kk < 4; kk++){
        const uint4 a = ap[kk];
        mixlo(yac[8*kk+0], a.x, e); mixhi(yac[8*kk+1], a.x, e);
        mixlo(yac[8*kk+2], a.y, e); mixhi(yac[8*kk+3], a.y, e);
        mixlo(yac[8*kk+4], a.z, e); mixhi(yac[8*kk+5], a.z, e);
        mixlo(yac[8*kk+6], a.w, e); mixhi(yac[8*kk+7], a.w, e);
      }
    }
  }

  const float inv = 1.f / esum;
  unsigned yw[16];
  #pragma unroll
  for (int k = 0; k < 16; k++) yw[k] = pkh(yac[2*k] * inv, yac[2*k+1] * inv);
  uint4* yp = (uint4*)(y2 + (size_t)((bb << 18) + (yy << 9) + xx) * 16);
  #pragma unroll
  for (int k = 0; k < 4; k++)
    yp[k] = make_uint4(yw[4*k], yw[4*k+1], yw[4*k+2], yw[4*k+3]);
}

// -------- K3: BN stats over f16 y2 ---------------------------------------------------
__global__ __launch_bounds__(256) void k3_stats(const unsigned* __restrict__ y2,
                                                float* __restrict__ stats){
  float s[COc], q[COc];
  #pragma unroll
  for (int o = 0; o < COc; o++){ s[o] = 0.f; q[o] = 0.f; }
  const int stride = gridDim.x * 256;
  for (int p = blockIdx.x * 256 + threadIdx.x; p < NPIXc; p += stride){
    const uint4* yp = (const uint4*)(y2 + (size_t)p * 16);
    #pragma unroll
    for (int k = 0; k < 4; k++){
      const uint4 w = yp[k];
      const unsigned vv[4] = {w.x, w.y, w.z, w.w};
      #pragma unroll
      for (int m = 0; m < 4; m++){
        const float2 ab = upk(vv[m]);
        s[8*k+2*m]   += ab.x; q[8*k+2*m]   = fmaf(ab.x, ab.x, q[8*k+2*m]);
        s[8*k+2*m+1] += ab.y; q[8*k+2*m+1] = fmaf(ab.y, ab.y, q[8*k+2*m+1]);
      }
    }
  }
  #pragma unroll
  for (int o = 0; o < COc; o++){
    #pragma unroll
    for (int off = 32; off; off >>= 1){
      s[o] += __shfl_down(s[o], off);
      q[o] += __shfl_down(q[o], off);
    }
  }
  __shared__ float red[4][64];
  const int wv = threadIdx.x >> 6;
  if ((threadIdx.x & 63) == 0){
    #pragma unroll
    for (int o = 0; o < COc; o++){ red[wv][o] = s[o]; red[wv][32 + o] = q[o]; }
  }
  __syncthreads();
  if (threadIdx.x < 64){
    const float v = red[0][threadIdx.x] + red[1][threadIdx.x]
                  + red[2][threadIdx.x] + red[3][threadIdx.x];
    atomicAdd(&stats[threadIdx.x], v);
  }
}

// -------- K3b: stats -> (mean, 0.1*rsqrt(var+eps)) ------------------------------------
__global__ void k3b_final(const float* __restrict__ stats, float* __restrict__ stats2){
  const int t = threadIdx.x;
  if (t < COc){
    const float invN = 1.f / (float)NPIXc;
    const float mean = stats[t] * invN;
    const float var  = fmaf(-mean, mean, stats[COc + t] * invN);
    stats2[t]       = mean;
    stats2[COc + t] = 0.1f * rsqrtf(var + 1e-5f);
  }
}

// -------- K4: BatchNorm + residual ----------------------------------------------------
__global__ __launch_bounds__(256) void k4_out(const unsigned* __restrict__ y2,
                                              const float* __restrict__ alpha,
                                              const float* __restrict__ stats2,
                                              float* __restrict__ out){
  const int p   = blockIdx.x * 256 + threadIdx.x;
  const int b   = p >> 18;
  const int pix = p & (HWc - 1);
  const uint4* yp = (const uint4*)(y2 + (size_t)p * 16);
  const size_t boff = (size_t)b * COc * HWc + pix;
  #pragma unroll
  for (int k = 0; k < 4; k++){
    const uint4 w = yp[k];
    const unsigned vv[4] = {w.x, w.y, w.z, w.w};
    #pragma unroll
    for (int m = 0; m < 4; m++){
      const int o = 8*k + 2*m;
      const float2 ab = upk(vv[m]);
      out[boff + (size_t)o*HWc]     = fmaf(ab.x - stats2[o],   stats2[COc+o],
                                           alpha[boff + (size_t)o*HWc]);
      out[boff + (size_t)(o+1)*HWc] = fmaf(ab.y - stats2[o+1], stats2[COc+o+1],
                                           alpha[boff + (size_t)(o+1)*HWc]);
    }
  }
}

extern "C" void kernel_launch(void* const* d_in, const int* in_sizes, int n_in,
                              void* d_out, int out_size, void* d_ws, size_t ws_size,
                              hipStream_t stream){
  const float* f     = (const float*)d_in[0];
  const float* alpha = (const float*)d_in[1];
  const float* wg    = (const float*)d_in[2];
  const float* bg    = (const float*)d_in[3];
  const float* wbar  = (const float*)d_in[4];
  const float* u     = (const float*)d_in[5];
  (void)in_sizes; (void)n_in; (void)out_size; (void)ws_size;
  float* out = (float*)d_out;

  char* ws = (char*)d_ws;
  float*    stats  = (float*)ws;                       // 256 B
  float*    stats2 = (float*)(ws + 4096);              // 256 B
  unsigned* wgA    = (unsigned*)(ws + 8192);           // 16 KB
  unsigned* wsnA   = (unsigned*)(ws + 32768);          // 2 KB
  unsigned* apm    = (unsigned*)(ws + 65536);                                   // 32 MB
  unsigned* gn     = (unsigned*)(ws + 65536 + (size_t)NPIXc*64);                // 64 MB
  unsigned* y2     = (unsigned*)(ws + 65536 + (size_t)NPIXc*64 + (size_t)NPIXc*128); // 32 MB

  (void)hipMemsetAsync(stats, 0, 64 * sizeof(float), stream);
  k0_prep  <<<1, 64, 0, stream>>>(wbar, u, wg, wgA, wsnA);
  k1m      <<<NPIXc / 256, 256, 0, stream>>>(f, alpha, (const uint4*)wgA,
                                             (const uint4*)wsnA, bg, gn, apm);
  k2_agg   <<<2048, 256, 0, stream>>>(gn, apm, y2);
  k3_stats <<<256, 256, 0, stream>>>(y2, stats);
  k3b_final<<<1, 64, 0, stream>>>(stats, stats2);
  k4_out   <<<NPIXc / 256, 256, 0, stream>>>(y2, alpha, stats2, out);
}

// Round 14
// 309.012 us; speedup vs baseline: 1.4898x; 1.0068x over previous
//
#include <hip/hip_runtime.h>

#define HWc   262144   // 512*512
#define CGc   128
#define CHc   64
#define COc   32
#define NPIXc 524288   // B*H*W
#define TW 32
#define TH 8
#define HLW 38         // TW+6
#define HLH 14         // TH+6
#define HPX (HLW*HLH)  // 532

typedef _Float16 h2    __attribute__((ext_vector_type(2)));
typedef __fp16   fp2   __attribute__((ext_vector_type(2)));
typedef _Float16 f16x8 __attribute__((ext_vector_type(8)));
typedef float    f32x4 __attribute__((ext_vector_type(4)));

union AB { uint4 q; f16x8 v; h2 p[4]; unsigned u[4]; };

__device__ __forceinline__ int refl(int p){
  if (p < 0) p = -p;
  else if (p >= 512) p = 1022 - p;
  return p;
}
__device__ __forceinline__ h2 as_h2(unsigned u){ union{unsigned u; h2 h;} x; x.u = u; return x.h; }
__device__ __forceinline__ unsigned as_u(h2 h){ union{unsigned u; h2 h;} x; x.h = h; return x.u; }
__device__ __forceinline__ unsigned pkh(float a, float b){       // RNE pack
  h2 h; h.x = (_Float16)a; h.y = (_Float16)b; return as_u(h);
}
__device__ __forceinline__ h2 pkrtz(float a, float b){           // v_cvt_pkrtz
  union{ fp2 f; h2 h; } x; x.f = __builtin_amdgcn_cvt_pkrtz(a, b); return x.h;
}
__device__ __forceinline__ float2 upk(unsigned u){
  h2 h = as_h2(u); return make_float2((float)h.x, (float)h.y);
}
__device__ __forceinline__ float dot2h(unsigned a, unsigned b, float c){
  return __builtin_amdgcn_fdot2(as_h2(a), as_h2(b), c, false);
}
// packed f16 fma: d = a*b + c on 2 f16 lanes (VOP3P) — 2 channels per op
__device__ __forceinline__ unsigned pkfma16(unsigned a, unsigned b, unsigned c){
  unsigned d;
  asm("v_pk_fma_f16 %0, %1, %2, %3" : "=v"(d) : "v"(a), "v"(b), "v"(c));
  return d;
}
__device__ __forceinline__ f32x4 mfma32(f16x8 a, f16x8 b, f32x4 c){
  return __builtin_amdgcn_mfma_f32_16x16x32_f16(a, b, c, 0, 0, 0);
}

// -------- K0: sigma; pack wg and w_sn into MFMA A-fragment order ----------------------
__global__ void k0_prep(const float* __restrict__ wbar, const float* __restrict__ u,
                        const float* __restrict__ wg,
                        unsigned* __restrict__ wgA, unsigned* __restrict__ wsnA){
  const int t = threadIdx.x;
  __shared__ float sv1[32];
  float tv = 0.f;
  if (t < 32){
    #pragma unroll
    for (int o = 0; o < 32; o++) tv += wbar[o*32 + t] * u[o];
  }
  float sq = tv * tv;
  #pragma unroll
  for (int off = 32; off; off >>= 1) sq += __shfl_down(sq, off);
  const float n1 = sqrtf(__shfl(sq, 0)) + 1e-12f;
  if (t < 32) sv1[t] = tv / n1;
  __syncthreads();
  float tu = 0.f;
  if (t < 32){
    #pragma unroll
    for (int c = 0; c < 32; c++) tu += wbar[t*32 + c] * sv1[c];
  }
  float sq2 = tu * tu;
  #pragma unroll
  for (int off = 32; off; off >>= 1) sq2 += __shfl_down(sq2, off);
  const float S = __shfl(sq2, 0);
  const float inv = (sqrtf(S) + 1e-12f) / S;     // 1/sigma

  for (int k = t; k < 4096; k += 64){
    const int mk = k >> 8, L = (k >> 2) & 63, j = k & 3;
    const int m = mk >> 2, ks = mk & 3;
    const int o = m*16 + (L & 15);
    const int c = ks*32 + 8*(L >> 4) + 2*j;
    wgA[k] = pkh(wg[o*128 + c], wg[o*128 + c + 1]);
  }
  for (int k = t; k < 512; k += 64){
    const int m = k >> 8, L = (k >> 2) & 63, j = k & 3;
    const int o = m*16 + (L & 15);
    const int c = 8*(L >> 4) + 2*j;
    wsnA[k] = pkh(wbar[o*32 + c] * inv, wbar[o*32 + c + 1] * inv);
  }
}

// -------- K1m: MFMA conv+norm / alpha' — 2-tile software pipeline ---------------------
__global__ __launch_bounds__(256) void k1m(const float* __restrict__ f,
                                           const float* __restrict__ alpha,
                                           const uint4* __restrict__ wgA,
                                           const uint4* __restrict__ wsnA,
                                           const float* __restrict__ bg,
                                           unsigned* __restrict__ gn,
                                           unsigned* __restrict__ apm){
  const int tid  = threadIdx.x;
  const int lane = tid & 63, w = tid >> 6;
  const int lo   = lane & 15, hi = lane >> 4;

  AB wga[4][4];
  #pragma unroll
  for (int m = 0; m < 4; m++)
    #pragma unroll
    for (int ks = 0; ks < 4; ks++)
      wga[m][ks].q = wgA[(m*4 + ks)*64 + lane];
  AB wsa[2];
  #pragma unroll
  for (int m = 0; m < 2; m++) wsa[m].q = wsnA[m*64 + lane];
  float4 bgl[4];
  #pragma unroll
  for (int m = 0; m < 4; m++) bgl[m] = *(const float4*)(bg + m*16 + hi*4);

  const int pxg = blockIdx.x * 256 + w * 64;

  auto loadT = [&](int nt, float* fv, float* av){
    const int px0  = pxg + nt*16;
    const int b    = px0 >> 18;
    const int pix0 = px0 & (HWc - 1);
    const float* fb = f + (size_t)b * CGc * HWc + pix0 + lo;
    const float* ac = alpha + (size_t)b * COc * HWc + pix0 + lo + (size_t)(hi*8) * HWc;
    #pragma unroll
    for (int ks = 0; ks < 4; ks++){
      const float* fc = fb + (size_t)(ks*32 + hi*8) * HWc;
      #pragma unroll
      for (int e = 0; e < 8; e++)
        fv[ks*8 + e] = fc[(size_t)e * HWc];
    }
    #pragma unroll
    for (int e = 0; e < 8; e++)
      av[e] = ac[(size_t)e * HWc];
  };

  auto procT = [&](int nt, const float* fv, const float* av){
    const int px0  = pxg + nt*16;

    f32x4 acc[4];
    #pragma unroll
    for (int m = 0; m < 4; m++) acc[m] = (f32x4){0.f, 0.f, 0.f, 0.f};

    #pragma unroll
    for (int ks = 0; ks < 4; ks++){
      AB bf;
      #pragma unroll
      for (int j = 0; j < 4; j++)
        bf.p[j] = pkrtz(fv[ks*8 + 2*j], fv[ks*8 + 2*j + 1]);
      #pragma unroll
      for (int m = 0; m < 4; m++)
        acc[m] = mfma32(wga[m][ks].v, bf.v, acc[m]);
    }

    float v[16]; float nsq = 0.f;
    #pragma unroll
    for (int m = 0; m < 4; m++){
      v[4*m+0] = acc[m][0] + bgl[m].x;
      v[4*m+1] = acc[m][1] + bgl[m].y;
      v[4*m+2] = acc[m][2] + bgl[m].z;
      v[4*m+3] = acc[m][3] + bgl[m].w;
      nsq = fmaf(v[4*m+0], v[4*m+0], nsq); nsq = fmaf(v[4*m+1], v[4*m+1], nsq);
      nsq = fmaf(v[4*m+2], v[4*m+2], nsq); nsq = fmaf(v[4*m+3], v[4*m+3], nsq);
    }
    nsq += __shfl_xor(nsq, 16);
    nsq += __shfl_xor(nsq, 32);
    const float inv = 1.f / fmaxf(sqrtf(nsq), 1e-4f);

    unsigned* gp = gn + (size_t)(px0 + lo) * 32 + hi*2;
    #pragma unroll
    for (int m = 0; m < 4; m++){
      uint2 st = make_uint2(pkh(v[4*m+0]*inv, v[4*m+1]*inv),
                            pkh(v[4*m+2]*inv, v[4*m+3]*inv));
      *(uint2*)(gp + m*8) = st;
    }

    AB af;
    #pragma unroll
    for (int j = 0; j < 4; j++)
      af.p[j] = pkrtz(av[2*j], av[2*j + 1]);
    unsigned* op = apm + (size_t)(px0 + lo) * 16 + hi*2;
    #pragma unroll
    for (int m = 0; m < 2; m++){
      f32x4 aa = (f32x4){0.f, 0.f, 0.f, 0.f};
      aa = mfma32(wsa[m].v, af.v, aa);
      uint2 st = make_uint2(pkh(aa[0], aa[1]), pkh(aa[2], aa[3]));
      *(uint2*)(op + m*8) = st;
    }
  };

  float fv0[32], av0[8], fv1[32], av1[8];
  loadT(0, fv0, av0);
  loadT(1, fv1, av1);
  procT(0, fv0, av0);
  loadT(2, fv0, av0);
  procT(1, fv1, av1);
  loadT(3, fv1, av1);
  procT(2, fv0, av0);
  procT(3, fv1, av1);
}

// -------- K2: dot2 correlation + softmax + pk_fma_f16 aggregation -> y2 f16 ----------
__global__ __launch_bounds__(256) void k2_agg(const unsigned* __restrict__ gn,
                                              const unsigned* __restrict__ apm,
                                              unsigned* __restrict__ y2){
  __shared__ uint4 gs4[8][HPX];   // 68 KB: full halo, 8 channel-pair planes

  const int lb  = (blockIdx.x & 7) * 256 + (blockIdx.x >> 3);   // XCD-chunked swizzle
  const int txx = lb & 15;
  const int tyy = (lb >> 4) & 63;
  const int bb  = lb >> 10;
  const int x0  = txx * TW, y0 = tyy * TH;
  const int tid = threadIdx.x;

  for (int t = tid; t < HPX; t += 256){
    const int hr = t / HLW;
    const int hc = t - hr * HLW;
    const int gy = refl(y0 + hr - 3);
    const int gx = refl(x0 + hc - 3);
    const uint4* src = (const uint4*)(gn + (size_t)((bb << 18) + (gy << 9) + gx) * 32);
    #pragma unroll
    for (int k = 0; k < 8; k++) gs4[k][t] = src[k];
  }
  __syncthreads();

  const int r  = tid >> 5, c = tid & 31;
  const int yy = y0 + r,  xx = x0 + c;
  const int self = (r + 3) * HLW + (c + 3);

  uint4 cv[8];
  #pragma unroll
  for (int k = 0; k < 8; k++) cv[k] = gs4[k][self];

  int ax[7];
  #pragma unroll
  for (int j = 0; j < 7; j++) ax[j] = refl(xx + j - 3);

  unsigned ya[16];   // 32 channels as f16 pairs
  #pragma unroll
  for (int k = 0; k < 16; k++) ya[k] = 0u;
  float esum = 0.f;

  #pragma unroll 1
  for (int i = 0; i < 7; i++){
    const int ay = refl(yy + i - 3);
    const unsigned* aprow = apm + (size_t)((bb << 18) + (ay << 9)) * 16;
    const int rowbase = (r + i) * HLW + c;
    #pragma unroll
    for (int j = 0; j < 7; j++){
      if (i == 3 && j == 3) continue;          // center tap: exp(-10000) == 0
      const int hp = rowbase + j;
      float s0 = 0.f, s1 = 0.f, s2 = 0.f, s3 = 0.f;
      #pragma unroll
      for (int k = 0; k < 8; k++){
        const uint4 q = gs4[k][hp];
        s0 = dot2h(cv[k].x, q.x, s0);
        s1 = dot2h(cv[k].y, q.y, s1);
        s2 = dot2h(cv[k].z, q.z, s2);
        s3 = dot2h(cv[k].w, q.w, s3);
      }
      const float e = __expf((s0 + s1) + (s2 + s3));
      esum += e;
      const unsigned eh = as_u(pkrtz(e, e));   // e broadcast to both f16 lanes
      const uint4* ap = (const uint4*)(aprow + (size_t)ax[j] * 16);
      #pragma unroll
      for (int kk = 0; kk < 4; kk++){
        const uint4 a = ap[kk];
        ya[4*kk+0] = pkfma16(a.x, eh, ya[4*kk+0]);
        ya[4*kk+1] = pkfma16(a.y, eh, ya[4*kk+1]);
        ya[4*kk+2] = pkfma16(a.z, eh, ya[4*kk+2]);
        ya[4*kk+3] = pkfma16(a.w, eh, ya[4*kk+3]);
      }
    }
  }

  const float inv = 1.f / esum;
  unsigned yw[16];
  #pragma unroll
  for (int k = 0; k < 16; k++){
    const float2 t2 = upk(ya[k]);
    yw[k] = pkh(t2.x * inv, t2.y * inv);
  }
  uint4* yp = (uint4*)(y2 + (size_t)((bb << 18) + (yy << 9) + xx) * 16);
  #pragma unroll
  for (int k = 0; k < 4; k++)
    yp[k] = make_uint4(yw[4*k], yw[4*k+1], yw[4*k+2], yw[4*k+3]);
}

// -------- K3: BN stats over f16 y2 ---------------------------------------------------
__global__ __launch_bounds__(256) void k3_stats(const unsigned* __restrict__ y2,
                                                float* __restrict__ stats){
  float s[COc], q[COc];
  #pragma unroll
  for (int o = 0; o < COc; o++){ s[o] = 0.f; q[o] = 0.f; }
  const int stride = gridDim.x * 256;
  for (int p = blockIdx.x * 256 + threadIdx.x; p < NPIXc; p += stride){
    const uint4* yp = (const uint4*)(y2 + (size_t)p * 16);
    #pragma unroll
    for (int k = 0; k < 4; k++){
      const uint4 w = yp[k];
      const unsigned vv[4] = {w.x, w.y, w.z, w.w};
      #pragma unroll
      for (int m = 0; m < 4; m++){
        const float2 ab = upk(vv[m]);
        s[8*k+2*m]   += ab.x; q[8*k+2*m]   = fmaf(ab.x, ab.x, q[8*k+2*m]);
        s[8*k+2*m+1] += ab.y; q[8*k+2*m+1] = fmaf(ab.y, ab.y, q[8*k+2*m+1]);
      }
    }
  }
  #pragma unroll
  for (int o = 0; o < COc; o++){
    #pragma unroll
    for (int off = 32; off; off >>= 1){
      s[o] += __shfl_down(s[o], off);
      q[o] += __shfl_down(q[o], off);
    }
  }
  __shared__ float red[4][64];
  const int wv = threadIdx.x >> 6;
  if ((threadIdx.x & 63) == 0){
    #pragma unroll
    for (int o = 0; o < COc; o++){ red[wv][o] = s[o]; red[wv][32 + o] = q[o]; }
  }
  __syncthreads();
  if (threadIdx.x < 64){
    const float v = red[0][threadIdx.x] + red[1][threadIdx.x]
                  + red[2][threadIdx.x] + red[3][threadIdx.x];
    atomicAdd(&stats[threadIdx.x], v);
  }
}

// -------- K3b: stats -> (mean, 0.1*rsqrt(var+eps)) ------------------------------------
__global__ void k3b_final(const float* __restrict__ stats, float* __restrict__ stats2){
  const int t = threadIdx.x;
  if (t < COc){
    const float invN = 1.f / (float)NPIXc;
    const float mean = stats[t] * invN;
    const float var  = fmaf(-mean, mean, stats[COc + t] * invN);
    stats2[t]       = mean;
    stats2[COc + t] = 0.1f * rsqrtf(var + 1e-5f);
  }
}

// -------- K4: BatchNorm + residual ----------------------------------------------------
__global__ __launch_bounds__(256) void k4_out(const unsigned* __restrict__ y2,
                                              const float* __restrict__ alpha,
                                              const float* __restrict__ stats2,
                                              float* __restrict__ out){
  const int p   = blockIdx.x * 256 + threadIdx.x;
  const int b   = p >> 18;
  const int pix = p & (HWc - 1);
  const uint4* yp = (const uint4*)(y2 + (size_t)p * 16);
  const size_t boff = (size_t)b * COc * HWc + pix;
  #pragma unroll
  for (int k = 0; k < 4; k++){
    const uint4 w = yp[k];
    const unsigned vv[4] = {w.x, w.y, w.z, w.w};
    #pragma unroll
    for (int m = 0; m < 4; m++){
      const int o = 8*k + 2*m;
      const float2 ab = upk(vv[m]);
      out[boff + (size_t)o*HWc]     = fmaf(ab.x - stats2[o],   stats2[COc+o],
                                           alpha[boff + (size_t)o*HWc]);
      out[boff + (size_t)(o+1)*HWc] = fmaf(ab.y - stats2[o+1], stats2[COc+o+1],
                                           alpha[boff + (size_t)(o+1)*HWc]);
    }
  }
}

extern "C" void kernel_launch(void* const* d_in, const int* in_sizes, int n_in,
                              void* d_out, int out_size, void* d_ws, size_t ws_size,
                              hipStream_t stream){
  const float* f     = (const float*)d_in[0];
  const float* alpha = (const float*)d_in[1];
  const float* wg    = (const float*)d_in[2];
  const float* bg    = (const float*)d_in[3];
  const float* wbar  = (const float*)d_in[4];
  const float* u     = (const float*)d_in[5];
  (void)in_sizes; (void)n_in; (void)out_size; (void)ws_size;
  float* out = (float*)d_out;

  char* ws = (char*)d_ws;
  float*    stats  = (float*)ws;                       // 256 B
  float*    stats2 = (float*)(ws + 4096);              // 256 B
  unsigned* wgA    = (unsigned*)(ws + 8192);           // 16 KB
  unsigned* wsnA   = (unsigned*)(ws + 32768);          // 2 KB
  unsigned* apm    = (unsigned*)(ws + 65536);                                   // 32 MB
  unsigned* gn     = (unsigned*)(ws + 65536 + (size_t)NPIXc*64);                // 64 MB
  unsigned* y2     = (unsigned*)(ws + 65536 + (size_t)NPIXc*64 + (size_t)NPIXc*128); // 32 MB

  (void)hipMemsetAsync(stats, 0, 64 * sizeof(float), stream);
  k0_prep  <<<1, 64, 0, stream>>>(wbar, u, wg, wgA, wsnA);
  k1m      <<<NPIXc / 256, 256, 0, stream>>>(f, alpha, (const uint4*)wgA,
                                             (const uint4*)wsnA, bg, gn, apm);
  k2_agg   <<<2048, 256, 0, stream>>>(gn, apm, y2);
  k3_stats <<<256, 256, 0, stream>>>(y2, stats);
  k3b_final<<<1, 64, 0, stream>>>(stats, stats2);
  k4_out   <<<NPIXc / 256, 256, 0, stream>>>(y2, alpha, stats2, out);
}